// Round 2
// baseline (15488.182 us; speedup 1.0000x reference)
//
#include <hip/hip_runtime.h>
#include <hip/hip_bf16.h>
#include <stdint.h>

// Problem constants (from reference)
#define VOCAB 400000
#define EMB_D 50
#define RNN   512
#define HID   1024
#define SEQ   8192

// Canary marking "H slot not yet written". tanh output is in (-1,1) and h0=0,
// so a stored value can never equal 2.0f. Data word doubles as readiness flag
// -> no release/acquire fences needed (per-element producer/consumer).
#define CANARY_BITS 0x40000000u   // 2.0f

// Poll cap: converts a pathological co-residency failure into a wrong answer
// instead of a hang. 65536 polls ~ 8 ms worst case -- never trips in practice.
#define SPIN_CAP 65536

// ---------------------------------------------------------------------------
// K_detect: decide whether token buffers are int32 or int64.
// If int64 (little-endian), the high dword of each element is 0 (tokens < 2^31).
// We only touch the first 8192 dwords (safe for both layouts).
// flag = 1 -> int32, flag = 0 -> int64.
// ---------------------------------------------------------------------------
__global__ void k_detect(const unsigned int* s1, const unsigned int* s2,
                         unsigned int* flag) {
    __shared__ unsigned int red[256];
    unsigned int x = 0;
    for (int i = threadIdx.x; i < SEQ / 2; i += 256) {
        x |= s1[2 * i + 1];
        x |= s2[2 * i + 1];
    }
    red[threadIdx.x] = x;
    __syncthreads();
    for (int s = 128; s > 0; s >>= 1) {
        if (threadIdx.x < s) red[threadIdx.x] |= red[threadIdx.x + s];
        __syncthreads();
    }
    if (threadIdx.x == 0) *flag = (red[0] != 0) ? 1u : 0u;
}

// ---------------------------------------------------------------------------
// K_init: H[0][:] = 0 (h0 = 0), H[1..SEQ][:] = canary. Both sequences.
// (d_ws is re-poisoned to 0xAA before every timed launch, so this must run
// every call.)
// ---------------------------------------------------------------------------
__global__ void k_init(float* HA, float* HB) {
    const size_t n = (size_t)(SEQ + 1) * RNN;
    const float canary = __uint_as_float(CANARY_BITS);
    size_t i = (size_t)blockIdx.x * blockDim.x + threadIdx.x;
    const size_t stride = (size_t)gridDim.x * blockDim.x;
    for (; i < n; i += stride) {
        float v = (i < RNN) ? 0.0f : canary;
        HA[i] = v;
        HB[i] = v;
    }
}

// ---------------------------------------------------------------------------
// K_xp: fused embedding gather + input projection.
//   XP[t][r] = sum_k emb[tok[t]][k] * W_ih[r][k]
// One block handles 64 timesteps; thread r holds W_ih row r in registers.
// ---------------------------------------------------------------------------
__global__ __launch_bounds__(512) void k_xp(const void* s_tok,
                                            const float* __restrict__ emb,
                                            const float* __restrict__ Wih,
                                            float* __restrict__ XP,
                                            const unsigned int* __restrict__ flag) {
    const int tb = blockIdx.x;      // 64-timestep chunk
    const int r  = threadIdx.x;     // output row 0..511
    const bool i32 = (*flag != 0);

    float wih[EMB_D];
#pragma unroll
    for (int k = 0; k < EMB_D; ++k) wih[k] = Wih[r * EMB_D + k];

    __shared__ float e[64];         // staged embedding row (50 used)

    for (int tt = 0; tt < 64; ++tt) {
        const int t = tb * 64 + tt;
        long long tok;
        if (i32) tok = (long long)((const int*)s_tok)[t];
        else     tok = ((const long long*)s_tok)[t];
        if (r < EMB_D) e[r] = emb[(size_t)tok * EMB_D + r];
        __syncthreads();
        float acc = 0.0f;
#pragma unroll
        for (int k = 0; k < EMB_D; ++k) acc = fmaf(wih[k], e[k], acc);
        XP[(size_t)t * RNN + r] = acc;
        __syncthreads();
    }
}

// ---------------------------------------------------------------------------
// rnn_rec: the serial recurrence, both sequences interleaved.
// Grid: 8 WGs x 512 threads. WG g owns rows [64g, 64g+64).
// Wave w (8 waves) owns column block [64w, 64w+64); lane l = row 64g+l.
// Each lane keeps 64 fp32 weights W_hh[64g+l][64w .. 64w+64) in VGPRs.
// h exchange via global H rings with device-scope relaxed atomics; the
// canary value doubles as the not-ready flag. Sequence B's compute phase
// hides sequence A's store->load L3 visibility latency and vice versa.
// ---------------------------------------------------------------------------
__global__ __launch_bounds__(512, 2) void rnn_rec(const float* __restrict__ XPA,
                                                  const float* __restrict__ XPB,
                                                  float* HA, float* HB,
                                                  const float* __restrict__ Whh) {
    const int g   = blockIdx.x;        // 0..7
    const int tid = threadIdx.x;
    const int w   = tid >> 6;          // wave 0..7
    const int l   = tid & 63;          // lane
    const int row = g * 64 + l;        // this lane's output row
    const int colbase = w * 64;        // this wave's column block

    __shared__ __align__(16) float hs[8][64];   // per-wave h staging
    __shared__ float P[8][64];                  // cross-wave partials
    __shared__ float h_ownA[64];                // WG's own fresh slice (seq A)
    __shared__ float h_ownB[64];                // WG's own fresh slice (seq B)

    // Load this lane's 64 weights into registers (W_hh read once from HBM).
    float wr[64];
    {
        const float* wp = Whh + (size_t)row * RNN + colbase;
#pragma unroll
        for (int j4 = 0; j4 < 16; ++j4) {
            float4 v = *(const float4*)(wp + 4 * j4);
            wr[4 * j4 + 0] = v.x;
            wr[4 * j4 + 1] = v.y;
            wr[4 * j4 + 2] = v.z;
            wr[4 * j4 + 3] = v.w;
        }
    }

    // xp prefetch registers (only wave 0 consumes them).
    float xpA_cur = 0.0f, xpB_cur = 0.0f;
    if (w == 0) {
        xpA_cur = XPA[row];
        xpB_cur = XPB[row];
    }

    // One recurrence phase for one sequence at timestep t.
    auto phase = [&](const float* __restrict__ XP, float* H, float* h_own,
                     float& xp_cur, int t) {
        // 1) obtain h[t] for my column block
        float hv;
        if (w == g && t > 0) {
            hv = h_own[l];   // own slice: short-circuit through LDS
        } else {
            unsigned int u;
            int tries = 0;
            do {
                u = __hip_atomic_load((unsigned int*)&H[(size_t)t * RNN + colbase + l],
                                      __ATOMIC_RELAXED, __HIP_MEMORY_SCOPE_AGENT);
            } while (__any((int)(u == CANARY_BITS)) && ++tries < SPIN_CAP);
            hv = __uint_as_float(u);
        }

        // 2) stage to LDS, broadcast-read, 64 FMAs.
        //    1-deep rotated loads: ds_read for iteration j+1 is issued while
        //    iteration j's FMAs execute (serial-critical-path latency hiding).
        hs[w][l] = hv;
        __builtin_amdgcn_wave_barrier();   // keep ds_write before ds_reads
        float a0 = 0.0f, a1 = 0.0f, a2 = 0.0f, a3 = 0.0f;
        float4 h4 = *(const float4*)&hs[w][0];     // wave-uniform -> broadcast
#pragma unroll
        for (int j4 = 0; j4 < 16; ++j4) {
            float4 cur = h4;
            if (j4 < 15) h4 = *(const float4*)&hs[w][4 * (j4 + 1)];
            a0 = fmaf(wr[4 * j4 + 0], cur.x, a0);
            a1 = fmaf(wr[4 * j4 + 1], cur.y, a1);
            a2 = fmaf(wr[4 * j4 + 2], cur.z, a2);
            a3 = fmaf(wr[4 * j4 + 3], cur.w, a3);
        }
        P[w][l] = (a0 + a1) + (a2 + a3);
        __syncthreads();

        // 3) wave 0 finalizes: reduce 8 partials, + xp, tanh, publish
        if (w == 0) {
            float s = 0.0f;
#pragma unroll
            for (int w2 = 0; w2 < 8; ++w2) s += P[w2][l];
            float hn = tanhf(s + xp_cur);
            __hip_atomic_store((unsigned int*)&H[(size_t)(t + 1) * RNN + g * 64 + l],
                               __float_as_uint(hn),
                               __ATOMIC_RELAXED, __HIP_MEMORY_SCOPE_AGENT);
            h_own[l] = hn;
            const int tn = (t + 1 < SEQ) ? (t + 1) : (SEQ - 1);
            xp_cur = XP[(size_t)tn * RNN + g * 64 + l];   // prefetch next step
        }
        __syncthreads();
    };

    for (int t = 0; t < SEQ; ++t) {
        phase(XPA, HA, h_ownA, xpA_cur, t);   // seq A
        phase(XPB, HB, h_ownB, xpB_cur, t);   // seq B (hides A's L3 latency)
    }
}

// ---------------------------------------------------------------------------
// K_hid: hid = relu(W_hid @ cat([h1;h2]) + b_hid). 32 blocks x 32 rows.
// ---------------------------------------------------------------------------
__global__ __launch_bounds__(1024) void k_hid(const float* HA, const float* HB,
                                              const float* __restrict__ Whid,
                                              const float* __restrict__ bhid,
                                              float* __restrict__ hid) {
    __shared__ float cat[2 * RNN];
    const int tid = threadIdx.x;
    cat[tid] = (tid < RNN) ? HA[(size_t)SEQ * RNN + tid]
                           : HB[(size_t)SEQ * RNN + (tid - RNN)];
    __syncthreads();

    const int rl  = tid >> 5;            // 0..31 row-in-block
    const int cl  = tid & 31;            // 0..31 column lane
    const int r   = blockIdx.x * 32 + rl;
    float acc = 0.0f;
#pragma unroll
    for (int i = 0; i < 32; ++i) {
        const int c = cl + 32 * i;
        acc = fmaf(Whid[(size_t)r * (2 * RNN) + c], cat[c], acc);
    }
    for (int d = 16; d > 0; d >>= 1) acc += __shfl_down(acc, d, 32);
    if (cl == 0) {
        float h = acc + bhid[r];
        hid[r] = (h > 0.0f) ? h : 0.0f;
    }
}

// ---------------------------------------------------------------------------
// K_out: out = sigmoid(W_out . hid + b_out)
// ---------------------------------------------------------------------------
__global__ __launch_bounds__(1024) void k_out(const float* __restrict__ hid,
                                              const float* __restrict__ Wout,
                                              const float* __restrict__ bout,
                                              float* __restrict__ out) {
    const int tid = threadIdx.x;
    float v = hid[tid] * Wout[tid];
    for (int d = 32; d > 0; d >>= 1) v += __shfl_down(v, d, 64);
    __shared__ float red[16];
    if ((tid & 63) == 0) red[tid >> 6] = v;
    __syncthreads();
    if (tid < 16) {
        float s = red[tid];
        for (int d = 8; d > 0; d >>= 1) s += __shfl_down(s, d, 16);
        if (tid == 0) out[0] = 1.0f / (1.0f + expf(-(s + bout[0])));
    }
}

// ---------------------------------------------------------------------------
// kernel_launch
// ---------------------------------------------------------------------------
extern "C" void kernel_launch(void* const* d_in, const int* in_sizes, int n_in,
                              void* d_out, int out_size, void* d_ws, size_t ws_size,
                              hipStream_t stream) {
    const void*  s1   = d_in[0];
    const void*  s2   = d_in[1];
    const float* emb  = (const float*)d_in[2];
    const float* Wih  = (const float*)d_in[3];
    const float* Whh  = (const float*)d_in[4];
    const float* Whid = (const float*)d_in[5];
    const float* bhid = (const float*)d_in[6];
    const float* Wout = (const float*)d_in[7];
    const float* bout = (const float*)d_in[8];
    float* out = (float*)d_out;

    // Workspace layout (fp32): XP_A | XP_B | H_A | H_B | hid | flag  (~67 MB)
    float* XPA  = (float*)d_ws;
    float* XPB  = XPA + (size_t)SEQ * RNN;
    float* HA   = XPB + (size_t)SEQ * RNN;
    float* HB   = HA + (size_t)(SEQ + 1) * RNN;
    float* hid  = HB + (size_t)(SEQ + 1) * RNN;
    unsigned int* flag = (unsigned int*)(hid + HID);

    k_detect<<<1, 256, 0, stream>>>((const unsigned int*)s1,
                                    (const unsigned int*)s2, flag);
    k_init<<<512, 256, 0, stream>>>(HA, HB);
    k_xp<<<SEQ / 64, 512, 0, stream>>>(s1, emb, Wih, XPA, flag);
    k_xp<<<SEQ / 64, 512, 0, stream>>>(s2, emb, Wih, XPB, flag);
    // 8 blocks on 256 CUs: co-resident in practice; polls are spin-capped so a
    // pathological scheduling failure degrades to a wrong answer, not a hang.
    rnn_rec<<<8, 512, 0, stream>>>(XPA, XPB, HA, HB, Whh);
    k_hid<<<HID / 32, 1024, 0, stream>>>(HA, HB, Whid, bhid, hid);
    k_out<<<1, 1024, 0, stream>>>(hid, Wout, bout, out);
}